// Round 7
// baseline (112.569 us; speedup 1.0000x reference)
//
#include <hip/hip_runtime.h>
#include <math.h>

#define R_N 4096
#define D_N 4096
#define C_N 20
#define IMG_W_F 1216.0f
#define IMG_H_F 800.0f
#define SCORE_TH 0.05f
#define NMS_TH 0.5f
#define TOPK_N 100

// ---- workspace layout (units: 4-byte words); everything write-before-read ----
#define WF_WORDS   (128 * 2 * 64 * 4)                // Wfrag 256 KB
#define DETT_OFF   (WF_WORDS)                        // detT[20][4096] f32 = exp(det logits)
#define DETT_WORDS (20 * R_N)
#define DSUM_OFF   (DETT_OFF + DETT_WORDS)           // dsum_arr[256][20]
#define DMAX_OFF   (DSUM_OFF + 256 * 20)             // dmax_arr[256][20]

typedef short bf16x8 __attribute__((ext_vector_type(8)));
typedef float f32x4  __attribute__((ext_vector_type(4)));

// truncating bf16 pack: {hi16(a), hi16(b)} -> lo short = bf16(b), hi short = bf16(a)
__device__ __forceinline__ unsigned pk(float a, float b) {
  return __builtin_amdgcn_perm(__float_as_uint(a), __float_as_uint(b), 0x07060302u);
}
__device__ __forceinline__ float fexp(float x) { return __expf(x); }

// async global->LDS DMA, 16B per lane; LDS dest = wave-uniform base + lane*16
__device__ __forceinline__ void g2lds16(const float* g, float* l) {
  __builtin_amdgcn_global_load_lds(
      (const __attribute__((address_space(1))) unsigned*)g,
      (__attribute__((address_space(3))) unsigned*)l, 16, 0, 0);
}

__device__ __forceinline__ void load_clip_box(const float* boxes, int r, float* b) {
  b[0] = fminf(fmaxf(boxes[r * 4 + 0], 0.f), IMG_W_F);
  b[1] = fminf(fmaxf(boxes[r * 4 + 1], 0.f), IMG_H_F);
  b[2] = fminf(fmaxf(boxes[r * 4 + 2], 0.f), IMG_W_F);
  b[3] = fminf(fmaxf(boxes[r * 4 + 3], 0.f), IMG_H_F);
}

// ============ pack W_det -> frag-linear bf16 ============
// entry e: l=e&63, ct=(e>>6)&1, gs=e>>7
// holds B[k = gs*32 + (l>>4)*8 + j][col = ct*16 + (l&15)], j=0..7
__global__ __launch_bounds__(256) void wT_kernel(
    const float* __restrict__ Wd, uint4* __restrict__ Wfrag) {
  const int e = blockIdx.x * 256 + threadIdx.x;     // 64 blocks -> 16384
  const int l = e & 63;
  const int ct = (e >> 6) & 1;
  const int gs = e >> 7;
  const int c = ct * 16 + (l & 15);
  const int k0 = gs * 32 + (l >> 4) * 8;
  float w[8];
  if (c < 21) {
#pragma unroll
    for (int j = 0; j < 8; j++) w[j] = Wd[(size_t)(k0 + j) * 21 + c];
  } else {
#pragma unroll
    for (int j = 0; j < 8; j++) w[j] = 0.f;
  }
  uint4 v;
  v.x = pk(w[1], w[0]); v.y = pk(w[3], w[2]);
  v.z = pk(w[5], w[4]); v.w = pk(w[7], w[6]);
  Wfrag[(gs * 2 + ct) * 64 + l] = v;
}

// ============ det GEMM: LDS double-buffered A via global_load_lds ============
// 256 blocks x 1024 thr (16 waves), block = 16 rows, K in 8 steps of 512.
// Stage: wave w DMAs ITS row (r0+w) step-slice (2 KB) to LDS with 2x
// global_load_lds dwordx4 (coalesced 1 KB/instr, zero VGPR). Source address
// carries the XOR swizzle (chunk ^= row&7, 16B chunks) since the LDS dest is
// forced linear; reads apply the same XOR -> conflict-free ds_read_b128.
// One barrier/step: compiler's vmcnt(0)+lgkmcnt(0) drain before s_barrier
// guarantees the staged data landed. Double buffer: step s+1 streams (HBM)
// while step s computes. Per-CU 32 KB in flight > ~22 KB Little's-law need.
// Compute: wave w does K sub-slice [s*512+w*32,+32) -> 2 MFMA/step.
// Epilogue: 16-way LDS reduce (reusing stage buf 0) -> exp -> ex-plane +
// per-block class sum/max planes. No atomics, no spins.
__global__ __launch_bounds__(1024) void detgemm_kernel(
    const float* __restrict__ x, const uint4* __restrict__ Wfrag,
    float* __restrict__ detT, float* __restrict__ dsum_arr,
    float* __restrict__ dmax_arr) {
  __shared__ float lds[2][16 * 512];                // 64 KB; lds[0] reused as red
  const int t = threadIdx.x;
  const int w = t >> 6, l = t & 63;
  const int r16 = l & 15, q = l >> 4;
  const int r0 = blockIdx.x * 16;
  const int swz = w & 7;                            // swizzle key of the row this wave stages
  const int rs = r16 & 7;                           // swizzle key of the row this lane reads

  const float* xw = x + (size_t)(r0 + w) * D_N;     // wave w stages row r0+w

#define STAGE(buf, s)                                                  \
  do {                                                                 \
    g2lds16(xw + (s) * 512 + ((l ^ swz) << 2),        &lds[buf][w * 512]);       \
    g2lds16(xw + (s) * 512 + (((64 | l) ^ swz) << 2), &lds[buf][w * 512 + 256]); \
  } while (0)

  STAGE(0, 0);
  __syncthreads();

  f32x4 acc0 = {0.f, 0.f, 0.f, 0.f};
  f32x4 acc1 = {0.f, 0.f, 0.f, 0.f};
  int cur = 0;
#pragma unroll
  for (int s = 0; s < 8; ++s) {
    if (s < 7) STAGE(cur ^ 1, s + 1);               // issue next-step DMA first
    const int gs = s * 16 + w;                      // K-chunk-of-32 index
    union { uint4 u; bf16x8 v; } b0, b1;
    b0.u = Wfrag[(gs * 2 + 0) * 64 + l];
    b1.u = Wfrag[(gs * 2 + 1) * 64 + l];
    const float* bb = &lds[cur][r16 * 512];
    const int c0 = w * 8 + q * 2;                   // even logical 16B-chunk
    float4 v0 = *(const float4*)(bb + ((c0)     ^ rs) * 4);
    float4 v1 = *(const float4*)(bb + ((c0 + 1) ^ rs) * 4);
    union { bf16x8 v; unsigned u[4]; } af;
    af.u[0] = pk(v0.y, v0.x);
    af.u[1] = pk(v0.w, v0.z);
    af.u[2] = pk(v1.y, v1.x);
    af.u[3] = pk(v1.w, v1.z);
    acc0 = __builtin_amdgcn_mfma_f32_16x16x32_bf16(af.v, b0.v, acc0, 0, 0, 0);
    acc1 = __builtin_amdgcn_mfma_f32_16x16x32_bf16(af.v, b1.v, acc1, 0, 0, 0);
    __syncthreads();                                // stage(s+1) landed; all reads of cur done
    cur ^= 1;
  }
#undef STAGE

  // lane l, reg j holds D[row=q*4+j][col=ct*16+r16]; red layout [w][c][r]
  float* red = lds[0];                              // stage buffers dead
  *(f32x4*)(&red[w * 512 + (0  + r16) * 16 + q * 4]) = acc0;
  *(f32x4*)(&red[w * 512 + (16 + r16) * 16 + q * 4]) = acc1;
  __syncthreads();
  if (t < 512) {                                    // t = c*16 + r
    float v = 0.f;
#pragma unroll
    for (int w2 = 0; w2 < 16; w2++) v += red[w2 * 512 + t];
    red[t] = v;                                     // full logit
  }
  __syncthreads();
  if (t < 320) {                                    // classes 0..19 only
    const int c = t >> 4, r = t & 15;
    float e = fexp(red[t]);
    detT[(size_t)c * R_N + r0 + r] = e;
    red[t] = e;                                     // own slot, reread after sync
  }
  __syncthreads();
  if (t < 20) {
    float s = 0.f, m = 0.f;
#pragma unroll
    for (int r = 0; r < 16; r++) {
      float e = red[t * 16 + r];
      s += e; m = fmaxf(m, e);
    }
    dsum_arr[blockIdx.x * 20 + t] = s;
    dmax_arr[blockIdx.x * 20 + t] = m;
  }
}

// ============ finale: ONE block, ~40 KB of reads, all state in LDS ============
// sd from dsum_arr (20 KB); dmax_arr prefilter (20 KB) -> worklist of flagged
// (block,class) pairs (<=20 blocks/class since sum(dsm)=1); scan only flagged
// 16-row strips of the ex-plane; then exact scores (on-demand cls GEMV), NMS,
// top-100 -- or the fast path when nothing passes threshold.
__global__ __launch_bounds__(1024) void finale_kernel(
    const float* __restrict__ x, const float* __restrict__ Wc,
    const float* __restrict__ b_cls, const float* __restrict__ detT,
    const float* __restrict__ dsum_arr, const float* __restrict__ dmax_arr,
    const float* __restrict__ boxes, float* __restrict__ out) {
  __shared__ float ps[640];
  __shared__ float sd[20];
  __shared__ float th[20];
  __shared__ int   wl[512];
  __shared__ int   n_wl;
  __shared__ int   nc[20];
  __shared__ int   cand_r[640];
  __shared__ float cand_d[640];
  __shared__ float cand_s[640];
  __shared__ int   s_ki[512];
  __shared__ float s_ks[512];
  __shared__ float sval[TOPK_N];
  __shared__ int   sidx[TOPK_N];
  __shared__ int   s_kc;
  __shared__ int   s_total;
  const int t = threadIdx.x;

  // ---- sd: per-class exp-sum = sum of 256 block partials ----
  if (t < 640) {                                    // c = t%20, group g = t/20
    const int c = t % 20, g = t / 20;
    float v = 0.f;
#pragma unroll
    for (int j = 0; j < 8; j++) v += dsum_arr[(g + 32 * j) * 20 + c];
    ps[t] = v;
  }
  if (t == 0) { n_wl = 0; s_kc = 0; }
  if (t < 20) nc[t] = 0;
  if (t < TOPK_N) { sval[t] = 0.f; sidx[t] = 0; }
  __syncthreads();
  if (t < 20) {
    float v = 0.f;
#pragma unroll
    for (int g = 0; g < 32; g++) v += ps[g * 20 + t];
    sd[t] = v;
    th[t] = SCORE_TH * v;                           // dsm > TH  <=>  ex > TH*sd
  }
  __syncthreads();

  // ---- prefilter: flag (block,class) pairs whose max ex exceeds threshold ----
  if (t < 640) {
    const int c = t % 20, g = t / 20;
#pragma unroll
    for (int j = 0; j < 8; j++) {
      const int b = g + 32 * j;
      if (dmax_arr[b * 20 + c] > th[c]) {
        int p = atomicAdd(&n_wl, 1);
        if (p < 512) wl[p] = b * 20 + c;
      }
    }
  }
  __syncthreads();

  // ---- scan only flagged 16-row strips ----
  int nw = n_wl; if (nw > 512) nw = 512;
  for (int i = t; i < nw; i += 1024) {
    const int e = wl[i];
    const int b = e / 20, c = e % 20;
    const float* dp = detT + (size_t)c * R_N + b * 16;
#pragma unroll
    for (int r = 0; r < 16; r++) {
      float ex = dp[r];
      if (ex > th[c]) {
        int p = atomicAdd(&nc[c], 1);
        if (p < 32) {
          cand_r[c * 32 + p] = b * 16 + r;
          cand_d[c * 32 + p] = ex / sd[c];
        }
      }
    }
  }
  __syncthreads();
  if (t == 0) {
    int tot = 0;
#pragma unroll
    for (int c = 0; c < 20; c++) tot += (nc[c] > 32 ? 32 : nc[c]);
    s_total = tot;
  }
  __syncthreads();

  if (s_total == 0) {
    // fast path: all scores below threshold -> top_k of zeros = indices 0..99
    if (t < TOPK_N) {
      int prop = t / C_N;
      int cls = t - prop * C_N;
      float b[4]; load_clip_box(boxes, prop, b);
      out[t] = 0.f;
      out[TOPK_N + t * 4 + 0] = b[0];
      out[TOPK_N + t * 4 + 1] = b[1];
      out[TOPK_N + t * 4 + 2] = b[2];
      out[TOPK_N + t * 4 + 3] = b[3];
      out[TOPK_N * 5 + t] = (float)cls;
    }
    return;
  }

  // ---- rare path: exact scores (cls GEMV on demand), NMS, top-100 ----
  for (int slot = t; slot < 640; slot += 1024) {
    const int c = slot >> 5, i = slot & 31;
    int n = nc[c]; if (n > 32) n = 32;
    if (i < n) {
      const int rr = cand_r[slot];
      float lg[21];
#pragma unroll
      for (int j = 0; j < 21; j++) lg[j] = b_cls[j];
      const float* xr = x + (size_t)rr * D_N;
      for (int k = 0; k < D_N; k++) {
        float xv = xr[k];
        const float* wr = Wc + (size_t)k * 21;
#pragma unroll
        for (int j = 0; j < 21; j++) lg[j] = fmaf(xv, wr[j], lg[j]);
      }
      float m = -1e30f;
#pragma unroll
      for (int j = 0; j < 21; j++) m = fmaxf(m, lg[j]);
      float s = 0.f;
#pragma unroll
      for (int j = 0; j < 21; j++) s += fexp(lg[j] - m);
      float p = fexp(lg[c] - m) / s;
      cand_s[slot] = p * cand_d[slot];
    }
  }
  __syncthreads();

  if (t < 20) {
    const int c = t;
    int n = nc[c]; if (n > 32) n = 32;
    float s[32]; int rr[32]; int n2 = 0;
    for (int i = 0; i < n; i++) {
      float sc = cand_s[c * 32 + i];
      if (sc > SCORE_TH) { s[n2] = sc; rr[n2] = cand_r[c * 32 + i]; n2++; }
    }
    for (int i = 1; i < n2; i++) {                  // score desc, tie -> row asc
      float si = s[i]; int ri = rr[i];
      int j = i - 1;
      while (j >= 0 && (s[j] < si || (s[j] == si && rr[j] > ri))) {
        s[j + 1] = s[j]; rr[j + 1] = rr[j]; j--;
      }
      s[j + 1] = si; rr[j + 1] = ri;
    }
    unsigned supp = 0;
    for (int i = 0; i < n2; i++) {
      if (supp & (1u << i)) continue;
      int g = atomicAdd(&s_kc, 1);
      if (g < 512) { s_ki[g] = rr[i] * C_N + c; s_ks[g] = s[i]; }
      float bi[4]; load_clip_box(boxes, rr[i], bi);
      float ai = (bi[2] - bi[0]) * (bi[3] - bi[1]);
      for (int j = i + 1; j < n2; j++) {
        if (supp & (1u << j)) continue;
        float bj[4]; load_clip_box(boxes, rr[j], bj);
        float aj = (bj[2] - bj[0]) * (bj[3] - bj[1]);
        float lx = fmaxf(bi[0], bj[0]), ly = fmaxf(bi[1], bj[1]);
        float rx = fminf(bi[2], bj[2]), ry = fminf(bi[3], bj[3]);
        float wdt = fmaxf(rx - lx, 0.f), hgt = fmaxf(ry - ly, 0.f);
        float inter = wdt * hgt;
        float iou = inter / (ai + aj - inter + 1e-9f);
        if (iou > NMS_TH) supp |= (1u << j);
      }
    }
  }
  __syncthreads();

  // ---- top-100 with jax.lax.top_k tie rules ----
  int m = s_kc; if (m > 512) m = 512;
  for (int i = t; i < m; i += 1024) {
    float si = s_ks[i]; int xi = s_ki[i];
    int rank = 0;
    for (int j = 0; j < m; j++) {
      float sj = s_ks[j]; int xj = s_ki[j];
      if (sj > si || (sj == si && xj < xi)) rank++;
    }
    if (rank < TOPK_N) { sval[rank] = si; sidx[rank] = xi; }
  }
  __syncthreads();
  if (t == 0) {
    int f = m < TOPK_N ? m : TOPK_N;
    int cur = 0;
    for (int slot = f; slot < TOPK_N; slot++) {
      for (;;) {
        bool member = false;
        for (int j = 0; j < m; j++)
          if (s_ki[j] == cur) { member = true; break; }
        if (!member) break;
        cur++;
      }
      sval[slot] = 0.f;
      sidx[slot] = cur;
      cur++;
    }
  }
  __syncthreads();
  if (t < TOPK_N) {
    int idx = sidx[t];
    int prop = idx / C_N;
    int cls = idx - prop * C_N;
    float b[4]; load_clip_box(boxes, prop, b);
    out[t] = sval[t];
    out[TOPK_N + t * 4 + 0] = b[0];
    out[TOPK_N + t * 4 + 1] = b[1];
    out[TOPK_N + t * 4 + 2] = b[2];
    out[TOPK_N + t * 4 + 3] = b[3];
    out[TOPK_N * 5 + t] = (float)cls;
  }
}

extern "C" void kernel_launch(void* const* d_in, const int* in_sizes, int n_in,
                              void* d_out, int out_size, void* d_ws, size_t ws_size,
                              hipStream_t stream) {
  const float* x     = (const float*)d_in[0];
  const float* boxes = (const float*)d_in[1];
  const float* W_cls = (const float*)d_in[2];
  const float* b_cls = (const float*)d_in[3];
  const float* W_det = (const float*)d_in[4];
  // b_det unused: column-softmax bias cancels

  float* out      = (float*)d_out;
  float* ws       = (float*)d_ws;
  uint4* Wfrag    = (uint4*)ws;
  float* detT     = ws + DETT_OFF;
  float* dsum_arr = ws + DSUM_OFF;
  float* dmax_arr = ws + DMAX_OFF;

  wT_kernel     <<<64,  256,  0, stream>>>(W_det, Wfrag);
  detgemm_kernel<<<256, 1024, 0, stream>>>(x, Wfrag, detT, dsum_arr, dmax_arr);
  finale_kernel <<<1,   1024, 0, stream>>>(x, W_cls, b_cls, detT,
                                           dsum_arr, dmax_arr, boxes, out);
}

// Round 9
// 112.068 us; speedup vs baseline: 1.0045x; 1.0045x over previous
//
#include <hip/hip_runtime.h>
#include <math.h>

#define R_N 4096
#define D_N 4096
#define C_N 20
#define IMG_W_F 1216.0f
#define IMG_H_F 800.0f
#define SCORE_TH 0.05f
#define NMS_TH 0.5f
#define TOPK_N 100

// ---- workspace layout (units: 4-byte words); everything write-before-read ----
#define WF_WORDS   (128 * 2 * 64 * 4)                // Wfrag 256 KB
#define DETT_OFF   (WF_WORDS)                        // detT[20][4096] f32 = exp(det logits)
#define DETT_WORDS (20 * R_N)
#define DSUM_OFF   (DETT_OFF + DETT_WORDS)           // dsum_arr[256][20]
#define DMAX_OFF   (DSUM_OFF + 256 * 20)             // dmax_arr[256][20]

typedef short bf16x8 __attribute__((ext_vector_type(8)));
typedef float f32x4  __attribute__((ext_vector_type(4)));

// truncating bf16 pack: {hi16(a), hi16(b)} -> lo short = bf16(b), hi short = bf16(a)
__device__ __forceinline__ unsigned pk(float a, float b) {
  return __builtin_amdgcn_perm(__float_as_uint(a), __float_as_uint(b), 0x07060302u);
}
__device__ __forceinline__ float fexp(float x) { return __expf(x); }

__device__ __forceinline__ void load_clip_box(const float* boxes, int r, float* b) {
  b[0] = fminf(fmaxf(boxes[r * 4 + 0], 0.f), IMG_W_F);
  b[1] = fminf(fmaxf(boxes[r * 4 + 1], 0.f), IMG_H_F);
  b[2] = fminf(fmaxf(boxes[r * 4 + 2], 0.f), IMG_W_F);
  b[3] = fminf(fmaxf(boxes[r * 4 + 3], 0.f), IMG_H_F);
}

// ============ pack W_det -> frag-linear bf16 ============
// entry e: l=e&63, ct=(e>>6)&1, gs=e>>7
// holds B[k = gs*32 + (l>>4)*8 + j][col = ct*16 + (l&15)], j=0..7
__global__ __launch_bounds__(256) void wT_kernel(
    const float* __restrict__ Wd, uint4* __restrict__ Wfrag) {
  const int e = blockIdx.x * 256 + threadIdx.x;     // 64 blocks -> 16384
  const int l = e & 63;
  const int ct = (e >> 6) & 1;
  const int gs = e >> 7;
  const int c = ct * 16 + (l & 15);
  const int k0 = gs * 32 + (l >> 4) * 8;
  float w[8];
  if (c < 21) {
#pragma unroll
    for (int j = 0; j < 8; j++) w[j] = Wd[(size_t)(k0 + j) * 21 + c];
  } else {
#pragma unroll
    for (int j = 0; j < 8; j++) w[j] = 0.f;
  }
  uint4 v;
  v.x = pk(w[1], w[0]); v.y = pk(w[3], w[2]);
  v.z = pk(w[5], w[4]); v.w = pk(w[7], w[6]);
  Wfrag[(gs * 2 + ct) * 64 + l] = v;
}

// ============ det GEMM, full K, Wfrag B, FORCED 16-deep A prefetch ============
// 256 blocks x 1024 thr (16 waves). Block = rows [b*16,+16); wave w: K
// [w*256,(w+1)*256). The 16 float4 A-loads are pinned by an asm-volatile
// KEEP-ALIVE that consumes every component (data dependence: no compiler
// pass can sink the loads past it -- sched_barrier alone failed in R3/R6,
// VGPR=32 evidence), sandwiched in sched_barrier(0). 64 VGPRs of A live
// at once -> all 16 loads in flight per wave, 256 KB/CU outstanding >>
// ~22 KB Little's-law need for HBM saturation. VGPR est ~102 < 128 cap.
// B: 2 x dwordx4 per K-chunk from L2-resident Wfrag. Epilogue: 16-way LDS
// reduce -> full logits -> exp -> ex-plane + per-block class sum/max.
__global__ __launch_bounds__(1024) void detgemm_kernel(
    const float* __restrict__ x, const uint4* __restrict__ Wfrag,
    float* __restrict__ detT, float* __restrict__ dsum_arr,
    float* __restrict__ dmax_arr) {
  __shared__ float red[16 * 512];                   // 32 KB
  const int t = threadIdx.x;
  const int w = t >> 6, l = t & 63;
  const int r16 = l & 15, q = l >> 4;
  const int r0 = blockIdx.x * 16;

  // ---- prefetch all A (16 rows x 256 K for this wave): 16 outstanding loads ----
  const float* xrow = x + (size_t)(r0 + r16) * D_N + w * 256 + q * 8;
  float4 a[16];
#pragma unroll
  for (int s = 0; s < 8; s++) {
    a[2 * s]     = *(const float4*)(xrow + s * 32);
    a[2 * s + 1] = *(const float4*)(xrow + s * 32 + 4);
  }
  __builtin_amdgcn_sched_barrier(0);
  // keep-alive: force all 16 float4s materialized HERE (loads issued above)
#pragma unroll
  for (int i = 0; i < 16; i++)
    asm volatile("" :: "v"(a[i].x), "v"(a[i].y), "v"(a[i].z), "v"(a[i].w));
  __builtin_amdgcn_sched_barrier(0);

  f32x4 acc0 = {0.f, 0.f, 0.f, 0.f};
  f32x4 acc1 = {0.f, 0.f, 0.f, 0.f};
#pragma unroll
  for (int s = 0; s < 8; s++) {
    const int gs = w * 8 + s;
    union { uint4 u; bf16x8 v; } b0, b1;
    b0.u = Wfrag[(gs * 2 + 0) * 64 + l];
    b1.u = Wfrag[(gs * 2 + 1) * 64 + l];
    union { bf16x8 v; unsigned u[4]; } af;
    af.u[0] = pk(a[2 * s].y,     a[2 * s].x);
    af.u[1] = pk(a[2 * s].w,     a[2 * s].z);
    af.u[2] = pk(a[2 * s + 1].y, a[2 * s + 1].x);
    af.u[3] = pk(a[2 * s + 1].w, a[2 * s + 1].z);
    acc0 = __builtin_amdgcn_mfma_f32_16x16x32_bf16(af.v, b0.v, acc0, 0, 0, 0);
    acc1 = __builtin_amdgcn_mfma_f32_16x16x32_bf16(af.v, b1.v, acc1, 0, 0, 0);
  }

  // lane l, reg j holds D[row=q*4+j][col=ct*16+r16]; red layout [w][c][r]
  *(f32x4*)(&red[w * 512 + (0  + r16) * 16 + q * 4]) = acc0;
  *(f32x4*)(&red[w * 512 + (16 + r16) * 16 + q * 4]) = acc1;
  __syncthreads();
  if (t < 512) {                                    // t = c*16 + r
    float v = 0.f;
#pragma unroll
    for (int w2 = 0; w2 < 16; w2++) v += red[w2 * 512 + t];
    red[t] = v;                                     // full logit
  }
  __syncthreads();
  if (t < 320) {                                    // classes 0..19 only
    const int c = t >> 4, r = t & 15;
    float e = fexp(red[t]);
    detT[(size_t)c * R_N + r0 + r] = e;
    red[t] = e;                                     // own slot, reread after sync
  }
  __syncthreads();
  if (t < 20) {
    float s = 0.f, m = 0.f;
#pragma unroll
    for (int r = 0; r < 16; r++) {
      float e = red[t * 16 + r];
      s += e; m = fmaxf(m, e);
    }
    dsum_arr[blockIdx.x * 20 + t] = s;
    dmax_arr[blockIdx.x * 20 + t] = m;
  }
}

// ============ finale: ONE block, ~40 KB of reads, all state in LDS ============
// sd from dsum_arr (20 KB); dmax_arr prefilter (20 KB) -> worklist of flagged
// (block,class) pairs (<=20 blocks/class since sum(dsm)=1); scan only flagged
// 16-row strips of the ex-plane; then exact scores (on-demand cls GEMV), NMS,
// top-100 -- or the fast path when nothing passes threshold.
__global__ __launch_bounds__(1024) void finale_kernel(
    const float* __restrict__ x, const float* __restrict__ Wc,
    const float* __restrict__ b_cls, const float* __restrict__ detT,
    const float* __restrict__ dsum_arr, const float* __restrict__ dmax_arr,
    const float* __restrict__ boxes, float* __restrict__ out) {
  __shared__ float ps[640];
  __shared__ float sd[20];
  __shared__ float th[20];
  __shared__ int   wl[512];
  __shared__ int   n_wl;
  __shared__ int   nc[20];
  __shared__ int   cand_r[640];
  __shared__ float cand_d[640];
  __shared__ float cand_s[640];
  __shared__ int   s_ki[512];
  __shared__ float s_ks[512];
  __shared__ float sval[TOPK_N];
  __shared__ int   sidx[TOPK_N];
  __shared__ int   s_kc;
  __shared__ int   s_total;
  const int t = threadIdx.x;

  // ---- sd: per-class exp-sum = sum of 256 block partials ----
  if (t < 640) {                                    // c = t%20, group g = t/20
    const int c = t % 20, g = t / 20;
    float v = 0.f;
#pragma unroll
    for (int j = 0; j < 8; j++) v += dsum_arr[(g + 32 * j) * 20 + c];
    ps[t] = v;
  }
  if (t == 0) { n_wl = 0; s_kc = 0; }
  if (t < 20) nc[t] = 0;
  if (t < TOPK_N) { sval[t] = 0.f; sidx[t] = 0; }
  __syncthreads();
  if (t < 20) {
    float v = 0.f;
#pragma unroll
    for (int g = 0; g < 32; g++) v += ps[g * 20 + t];
    sd[t] = v;
    th[t] = SCORE_TH * v;                           // dsm > TH  <=>  ex > TH*sd
  }
  __syncthreads();

  // ---- prefilter: flag (block,class) pairs whose max ex exceeds threshold ----
  if (t < 640) {
    const int c = t % 20, g = t / 20;
#pragma unroll
    for (int j = 0; j < 8; j++) {
      const int b = g + 32 * j;
      if (dmax_arr[b * 20 + c] > th[c]) {
        int p = atomicAdd(&n_wl, 1);
        if (p < 512) wl[p] = b * 20 + c;
      }
    }
  }
  __syncthreads();

  // ---- scan only flagged 16-row strips ----
  int nw = n_wl; if (nw > 512) nw = 512;
  for (int i = t; i < nw; i += 1024) {
    const int e = wl[i];
    const int b = e / 20, c = e % 20;
    const float* dp = detT + (size_t)c * R_N + b * 16;
#pragma unroll
    for (int r = 0; r < 16; r++) {
      float ex = dp[r];
      if (ex > th[c]) {
        int p = atomicAdd(&nc[c], 1);
        if (p < 32) {
          cand_r[c * 32 + p] = b * 16 + r;
          cand_d[c * 32 + p] = ex / sd[c];
        }
      }
    }
  }
  __syncthreads();
  if (t == 0) {
    int tot = 0;
#pragma unroll
    for (int c = 0; c < 20; c++) tot += (nc[c] > 32 ? 32 : nc[c]);
    s_total = tot;
  }
  __syncthreads();

  if (s_total == 0) {
    // fast path: all scores below threshold -> top_k of zeros = indices 0..99
    if (t < TOPK_N) {
      int prop = t / C_N;
      int cls = t - prop * C_N;
      float b[4]; load_clip_box(boxes, prop, b);
      out[t] = 0.f;
      out[TOPK_N + t * 4 + 0] = b[0];
      out[TOPK_N + t * 4 + 1] = b[1];
      out[TOPK_N + t * 4 + 2] = b[2];
      out[TOPK_N + t * 4 + 3] = b[3];
      out[TOPK_N * 5 + t] = (float)cls;
    }
    return;
  }

  // ---- rare path: exact scores (cls GEMV on demand), NMS, top-100 ----
  for (int slot = t; slot < 640; slot += 1024) {
    const int c = slot >> 5, i = slot & 31;
    int n = nc[c]; if (n > 32) n = 32;
    if (i < n) {
      const int rr = cand_r[slot];
      float lg[21];
#pragma unroll
      for (int j = 0; j < 21; j++) lg[j] = b_cls[j];
      const float* xr = x + (size_t)rr * D_N;
      for (int k = 0; k < D_N; k++) {
        float xv = xr[k];
        const float* wr = Wc + (size_t)k * 21;
#pragma unroll
        for (int j = 0; j < 21; j++) lg[j] = fmaf(xv, wr[j], lg[j]);
      }
      float m = -1e30f;
#pragma unroll
      for (int j = 0; j < 21; j++) m = fmaxf(m, lg[j]);
      float s = 0.f;
#pragma unroll
      for (int j = 0; j < 21; j++) s += fexp(lg[j] - m);
      float p = fexp(lg[c] - m) / s;
      cand_s[slot] = p * cand_d[slot];
    }
  }
  __syncthreads();

  if (t < 20) {
    const int c = t;
    int n = nc[c]; if (n > 32) n = 32;
    float s[32]; int rr[32]; int n2 = 0;
    for (int i = 0; i < n; i++) {
      float sc = cand_s[c * 32 + i];
      if (sc > SCORE_TH) { s[n2] = sc; rr[n2] = cand_r[c * 32 + i]; n2++; }
    }
    for (int i = 1; i < n2; i++) {                  // score desc, tie -> row asc
      float si = s[i]; int ri = rr[i];
      int j = i - 1;
      while (j >= 0 && (s[j] < si || (s[j] == si && rr[j] > ri))) {
        s[j + 1] = s[j]; rr[j + 1] = rr[j]; j--;
      }
      s[j + 1] = si; rr[j + 1] = ri;
    }
    unsigned supp = 0;
    for (int i = 0; i < n2; i++) {
      if (supp & (1u << i)) continue;
      int g = atomicAdd(&s_kc, 1);
      if (g < 512) { s_ki[g] = rr[i] * C_N + c; s_ks[g] = s[i]; }
      float bi[4]; load_clip_box(boxes, rr[i], bi);
      float ai = (bi[2] - bi[0]) * (bi[3] - bi[1]);
      for (int j = i + 1; j < n2; j++) {
        if (supp & (1u << j)) continue;
        float bj[4]; load_clip_box(boxes, rr[j], bj);
        float aj = (bj[2] - bj[0]) * (bj[3] - bj[1]);
        float lx = fmaxf(bi[0], bj[0]), ly = fmaxf(bi[1], bj[1]);
        float rx = fminf(bi[2], bj[2]), ry = fminf(bi[3], bj[3]);
        float wdt = fmaxf(rx - lx, 0.f), hgt = fmaxf(ry - ly, 0.f);
        float inter = wdt * hgt;
        float iou = inter / (ai + aj - inter + 1e-9f);
        if (iou > NMS_TH) supp |= (1u << j);
      }
    }
  }
  __syncthreads();

  // ---- top-100 with jax.lax.top_k tie rules ----
  int m = s_kc; if (m > 512) m = 512;
  for (int i = t; i < m; i += 1024) {
    float si = s_ks[i]; int xi = s_ki[i];
    int rank = 0;
    for (int j = 0; j < m; j++) {
      float sj = s_ks[j]; int xj = s_ki[j];
      if (sj > si || (sj == si && xj < xi)) rank++;
    }
    if (rank < TOPK_N) { sval[rank] = si; sidx[rank] = xi; }
  }
  __syncthreads();
  if (t == 0) {
    int f = m < TOPK_N ? m : TOPK_N;
    int cur = 0;
    for (int slot = f; slot < TOPK_N; slot++) {
      for (;;) {
        bool member = false;
        for (int j = 0; j < m; j++)
          if (s_ki[j] == cur) { member = true; break; }
        if (!member) break;
        cur++;
      }
      sval[slot] = 0.f;
      sidx[slot] = cur;
      cur++;
    }
  }
  __syncthreads();
  if (t < TOPK_N) {
    int idx = sidx[t];
    int prop = idx / C_N;
    int cls = idx - prop * C_N;
    float b[4]; load_clip_box(boxes, prop, b);
    out[t] = sval[t];
    out[TOPK_N + t * 4 + 0] = b[0];
    out[TOPK_N + t * 4 + 1] = b[1];
    out[TOPK_N + t * 4 + 2] = b[2];
    out[TOPK_N + t * 4 + 3] = b[3];
    out[TOPK_N * 5 + t] = (float)cls;
  }
}

extern "C" void kernel_launch(void* const* d_in, const int* in_sizes, int n_in,
                              void* d_out, int out_size, void* d_ws, size_t ws_size,
                              hipStream_t stream) {
  const float* x     = (const float*)d_in[0];
  const float* boxes = (const float*)d_in[1];
  const float* W_cls = (const float*)d_in[2];
  const float* b_cls = (const float*)d_in[3];
  const float* W_det = (const float*)d_in[4];
  // b_det unused: column-softmax bias cancels

  float* out      = (float*)d_out;
  float* ws       = (float*)d_ws;
  uint4* Wfrag    = (uint4*)ws;
  float* detT     = ws + DETT_OFF;
  float* dsum_arr = ws + DSUM_OFF;
  float* dmax_arr = ws + DMAX_OFF;

  wT_kernel     <<<64,  256,  0, stream>>>(W_det, Wfrag);
  detgemm_kernel<<<256, 1024, 0, stream>>>(x, Wfrag, detT, dsum_arr, dmax_arr);
  finale_kernel <<<1,   1024, 0, stream>>>(x, W_cls, b_cls, detT,
                                           dsum_arr, dmax_arr, boxes, out);
}